// Round 3
// baseline (129.879 us; speedup 1.0000x reference)
//
#include <hip/hip_runtime.h>

namespace {

constexpr int LMAX  = 10;
constexpr int NPART = 2;
// Balanced 2-way partition of l by inner-term count:
// P0{10,7,6,3,2} = 82 terms / 61 slots, P1{9,8,5,4,1,0} = 79 terms / 60 slots
constexpr int PART_OF_L[LMAX + 1] = {1, 1, 0, 0, 1, 1, 0, 0, 1, 1, 0};
constexpr double PI_D = 3.14159265358979323846;

constexpr double dfact(int n) {
    double r = 1.0;
    for (int i = 2; i <= n; ++i) r *= (double)i;
    return r;
}

constexpr double csqrt(double x) {
    if (x <= 0.0) return 0.0;
    double g = x > 1.0 ? x : 1.0;
    for (int i = 0; i < 100; ++i) g = 0.5 * (g + x / g);
    return g;
}

constexpr double FACT[LMAX + 1] = {1., 1., 2., 6., 24., 120., 720., 5040., 40320., 362880., 3628800.};

// ---- per-part accumulator slot layout -------------------------------------
// For each l in the part (ascending): (l+1) real slots (m=0..l), then l imag
// slots (m=1..l).
constexpr int slot_base(int part, int l) {
    int c = 0;
    for (int ll = 0; ll < l; ++ll)
        if (PART_OF_L[ll] == part) c += 2 * ll + 1;
    return c;
}
constexpr int nacc_part(int part) {
    int c = 0;
    for (int l = 0; l <= LMAX; ++l)
        if (PART_OF_L[l] == part) c += 2 * l + 1;
    return c;
}
constexpr int part_lmax(int part) {
    int mx = 0;
    for (int l = 0; l <= LMAX; ++l)
        if (PART_OF_L[l] == part) mx = l;
    return mx;
}
constexpr int slot_r(int part, int l, int m) { return slot_base(part, l) + m; }
constexpr int slot_i(int part, int l, int m) { return slot_base(part, l) + (l + 1) + (m - 1); }

constexpr int MAXNA = 61;  // max nacc_part over parts (P0: 5+7+13+15+21 = 61)

// Horner coefficient for the collapsed imag sum: (-1)^q / ((q+m)! q! (l-m-2q)!)
constexpr float ci_coef(int l, int m, int q) {
    const double c = 1.0 / (FACT[q + m] * FACT[q] * FACT[l - m - 2 * q]);
    return (q & 1) ? (float)(-c) : (float)c;
}

struct Tables {
    int   map[NPART][MAXNA];
    float scl[NPART][MAXNA];
};

constexpr Tables make_tables() {
    Tables t{};
    for (int part = 0; part < NPART; ++part) {
        for (int l = 0; l <= LMAX; ++l) {
            if (PART_OF_L[l] != part) continue;
            for (int m = 0; m <= l; ++m) {
                const int k = slot_r(part, l, m);
                const double scale =
                    csqrt(dfact(l + m) * dfact(l - m)) * csqrt((2 * l + 1) / (4.0 * PI_D));
                // T==1 pairs (m >= l-1, m>=1): the single inner coefficient
                // c = 1/(m! (l-m)!) is folded into the output scale, so the
                // kernel does a bare table*wrl fma for those slots.
                const double fold = (m >= 1 && (l - m) <= 1) ? 1.0 / (dfact(m) * dfact(l - m)) : 1.0;
                if (m == 0) {
                    t.map[part][k] = l * l + l;
                    t.scl[part][k] = (float)(scale * fold);
                } else {
                    const double f = csqrt(2.0) * ((m & 1) ? -1.0 : 1.0);
                    t.map[part][k] = l * l + l + m;
                    t.scl[part][k] = (float)(f * scale * fold);
                }
            }
            for (int m = 1; m <= l; ++m) {
                const int k = slot_i(part, l, m);
                const double scale =
                    csqrt(dfact(l + m) * dfact(l - m)) * csqrt((2 * l + 1) / (4.0 * PI_D));
                const double f    = csqrt(2.0) * ((m & 1) ? -1.0 : 1.0);
                const double fold = ((l - m) <= 1) ? 1.0 / (dfact(m) * dfact(l - m)) : 1.0;
                t.map[part][k] = l * l + l - m;
                t.scl[part][k] = (float)(f * scale * fold);
            }
        }
    }
    return t;
}

__constant__ Tables c_tab = make_tables();

}  // namespace

// Algebra (exact in fp up to reassociation):
//   z1 = (-x/2, -y/2), z2 = -conj(z1)  =>  only one power table needed.
//   real term:  zreal = Re(z1^p)^2 - Im(z1^q)^2            = sr[p] - si[q]
//   imag term:  Im(z1^p z2^q) = (-1)^q rho^q * Im(z1^m),   rho = |z1|^2
//   so the whole imag p-sum collapses to  zi[m] * Horner_q(+-c * rho^q).
//   T==1 (m >= l-1) pairs degenerate to a single fma with the coefficient
//   folded into the host-side scl table.
//
// 2-way l-split: halves the per-part replicated preamble vs 4-way and halves
// pos re-scan traffic (round-2 counters: FETCH 47->23.7 MB, instr -25%).
//
// Round-2 lesson: VGPR_Count=84 fits 6 waves/SIMD, but the 768-block grid
// capped residency at 3 blocks/CU -> VALUBusy fell to 55%, occupancy to 22%.
// Grid (not registers) was the residency limit.  This round launches
// 6 blocks/CU (1536) with identical codegen to restore latency hiding.
template <int PART>
__device__ __forceinline__ void sht_part(const float* __restrict__ pos,
                                         float* __restrict__ out, int n, int nblk) {
    constexpr int NA = nacc_part(PART);
    constexpr int PL = part_lmax(PART);

    float acc[NA];
#pragma unroll
    for (int k = 0; k < NA; ++k) acc[k] = 0.f;

    const int bid    = (int)(blockIdx.x >> 1);
    const int tid    = bid * 256 + (int)threadIdx.x;
    const int stride = nblk * 256;

    int   i = tid;
    float x = 0.f, y = 0.f, z0 = 0.f;
    if (i < n) {
        x  = pos[3 * i + 0];
        y  = pos[3 * i + 1];
        z0 = pos[3 * i + 2];
    }

    while (i < n) {
        // software-pipelined prefetch of the next point
        const int inext = i + stride;
        float     px = 0.f, py = 0.f, pz = 0.f;
        if (inext < n) {
            px = pos[3 * inext + 0];
            py = pos[3 * inext + 1];
            pz = pos[3 * inext + 2];
        }

        const float r2  = x * x + y * y + z0 * z0;
        const float nrm = sqrtf(r2);
        const float w0  = (nrm > 0.f) ? z0 : 0.f;  // x0 * mask

        const float ar = -0.5f * x, ai = -0.5f * y;
        const float rho = ar * ar + ai * ai;  // |z1|^2 = (x^2+y^2)/4

        // Power tables: zi[] (imag parts, needed for collapsed imag sums),
        // sr[p] = Re(z1^p)^2, si[p] = Im(z1^p)^2. Re(z1^p) is a rolling scalar.
        float zi[PL + 1], sr[PL + 1], si[PL + 1];
        zi[0] = 0.f;
        sr[0] = 1.f;
        si[0] = 0.f;
        float zrc = 1.f;
#pragma unroll
        for (int p = 1; p <= PL; ++p) {
            const float nzr = ar * zrc - ai * zi[p - 1];
            zi[p]           = ar * zi[p - 1] + ai * zrc;
            zrc             = nzr;
            sr[p]           = zrc * zrc;
            si[p]           = zi[p] * zi[p];
        }
        float rp[PL + 1];
        rp[0] = 1.f;
#pragma unroll
        for (int l = 1; l <= PL; ++l) rp[l] = rp[l - 1] * nrm;

#pragma unroll
        for (int l = 0; l <= LMAX; ++l) {
            if (PART_OF_L[l] != PART) continue;  // compile-time eliminated
            const float wrl = w0 * rp[l];
#pragma unroll
            for (int m = 0; m <= l; ++m) {
                const int Q = (l - m) >> 1;  // highest q in the sums
                if (m >= 1 && Q == 0) {
                    // single-term pair: coefficient folded into c_tab.scl
                    acc[slot_r(PART, l, m)] += sr[m] * wrl;
                    acc[slot_i(PART, l, m)] += zi[m] * wrl;
                } else {
                    float shr = 0.f;
#pragma unroll
                    for (int p = m; 2 * p <= l + m; ++p) {
                        const int   q  = p - m;
                        const float cr = (float)(1.0 / (FACT[p] * FACT[q] * FACT[l - 2 * p + m]));
                        shr += (sr[p] - si[q]) * cr;
                    }
                    acc[slot_r(PART, l, m)] += shr * wrl;
                    if (m >= 1) {
                        // shi = zi[m] * sum_q (+-c) rho^q   (Horner in rho)
                        float t = ci_coef(l, m, Q);
#pragma unroll
                        for (int q = Q - 1; q >= 0; --q) t = t * rho + ci_coef(l, m, q);
                        acc[slot_i(PART, l, m)] += (t * zi[m]) * wrl;
                    }
                }
            }
        }

        i  = inext;
        x  = px;
        y  = py;
        z0 = pz;
    }

    // Wave (64-lane) shuffle reduction, then cross-wave via LDS.
    __shared__ float red[4][NA];
    const int lane = threadIdx.x & 63;
    const int wav  = threadIdx.x >> 6;
#pragma unroll
    for (int k = 0; k < NA; ++k) {
        float v = acc[k];
#pragma unroll
        for (int off = 32; off > 0; off >>= 1) v += __shfl_down(v, off, 64);
        if (lane == 0) red[wav][k] = v;
    }
    __syncthreads();
    if ((int)threadIdx.x < NA) {
        const int   k = (int)threadIdx.x;
        const float v = red[0][k] + red[1][k] + red[2][k] + red[3][k];
        atomicAdd(&out[c_tab.map[PART][k]], v * c_tab.scl[PART][k]);
    }
}

__global__ __launch_bounds__(256, 3) void sht_kernel(const float* __restrict__ pos,
                                                     float* __restrict__ out, int n, int nblk) {
    // part = blockIdx & 1: under round-robin block->CU dispatch (stride 256,
    // 256 == 0 mod 2), all resident blocks on one CU share a part -> I$ locality.
    if (blockIdx.x & 1)
        sht_part<1>(pos, out, n, nblk);
    else
        sht_part<0>(pos, out, n, nblk);
}

extern "C" void kernel_launch(void* const* d_in, const int* in_sizes, int n_in,
                              void* d_out, int out_size, void* d_ws, size_t ws_size,
                              hipStream_t stream) {
    const float* pos = (const float*)d_in[0];
    float* out       = (float*)d_out;
    const int n      = in_sizes[0] / 3;  // (N,3) flat -> N points

    // d_out is poisoned before every launch; we accumulate via atomics.
    hipMemsetAsync(d_out, 0, (size_t)out_size * sizeof(float), stream);

    const int threads       = 256;
    // 768 blocks/part -> 1536 total = 6 blocks/CU: matches the 6 waves/SIMD
    // the measured 84-VGPR allocation supports (512/84 = 6), restoring
    // latency hiding that the round-2 768-block grid starved.  ~10 pts/thread
    // keeps the 61-slot shuffle epilogue at ~6% of per-wave work.
    const int nblk_per_part = 768;
    const int blocks        = NPART * nblk_per_part;  // 1536
    sht_kernel<<<blocks, threads, 0, stream>>>(pos, out, n, nblk_per_part);
}

// Round 4
// 120.211 us; speedup vs baseline: 1.0804x; 1.0804x over previous
//
#include <hip/hip_runtime.h>

namespace {

constexpr int LMAX  = 10;
constexpr int NPART = 2;
// Balanced 2-way partition of l by inner-term count:
// P0{10,7,6,3,2} = 82 terms / 61 slots, P1{9,8,5,4,1,0} = 79 terms / 60 slots
constexpr int PART_OF_L[LMAX + 1] = {1, 1, 0, 0, 1, 1, 0, 0, 1, 1, 0};
constexpr double PI_D = 3.14159265358979323846;

constexpr double dfact(int n) {
    double r = 1.0;
    for (int i = 2; i <= n; ++i) r *= (double)i;
    return r;
}

constexpr double csqrt(double x) {
    if (x <= 0.0) return 0.0;
    double g = x > 1.0 ? x : 1.0;
    for (int i = 0; i < 100; ++i) g = 0.5 * (g + x / g);
    return g;
}

constexpr double FACT[LMAX + 1] = {1., 1., 2., 6., 24., 120., 720., 5040., 40320., 362880., 3628800.};

// ---- per-part accumulator slot layout -------------------------------------
constexpr int slot_base(int part, int l) {
    int c = 0;
    for (int ll = 0; ll < l; ++ll)
        if (PART_OF_L[ll] == part) c += 2 * ll + 1;
    return c;
}
constexpr int nacc_part(int part) {
    int c = 0;
    for (int l = 0; l <= LMAX; ++l)
        if (PART_OF_L[l] == part) c += 2 * l + 1;
    return c;
}
constexpr int part_lmax(int part) {
    int mx = 0;
    for (int l = 0; l <= LMAX; ++l)
        if (PART_OF_L[l] == part) mx = l;
    return mx;
}
constexpr int nls(int part) {
    int c = 0;
    for (int l = 0; l <= LMAX; ++l)
        if (PART_OF_L[l] == part) ++c;
    return c;
}
constexpr int lidx(int part, int l) {
    int c = 0;
    for (int ll = 0; ll < l; ++ll)
        if (PART_OF_L[ll] == part) ++c;
    return c;
}
constexpr int slot_r(int part, int l, int m) { return slot_base(part, l) + m; }
constexpr int slot_i(int part, int l, int m) { return slot_base(part, l) + (l + 1) + (m - 1); }

constexpr int MAXNA = 61;  // max nacc_part over parts (P0: 5+7+13+15+21 = 61)

// Horner coefficient for the collapsed imag sum: (-1)^q / ((q+m)! q! (l-m-2q)!)
constexpr float ci_coef(int l, int m, int q) {
    const double c = 1.0 / (FACT[q + m] * FACT[q] * FACT[l - m - 2 * q]);
    return (q & 1) ? (float)(-c) : (float)c;
}

struct Tables {
    int   map[NPART][MAXNA];
    float scl[NPART][MAXNA];
};

constexpr Tables make_tables() {
    Tables t{};
    for (int part = 0; part < NPART; ++part) {
        for (int l = 0; l <= LMAX; ++l) {
            if (PART_OF_L[l] != part) continue;
            for (int m = 0; m <= l; ++m) {
                const int k = slot_r(part, l, m);
                const double scale =
                    csqrt(dfact(l + m) * dfact(l - m)) * csqrt((2 * l + 1) / (4.0 * PI_D));
                const double fold = (m >= 1 && (l - m) <= 1) ? 1.0 / (dfact(m) * dfact(l - m)) : 1.0;
                if (m == 0) {
                    t.map[part][k] = l * l + l;
                    t.scl[part][k] = (float)(scale * fold);
                } else {
                    const double f = csqrt(2.0) * ((m & 1) ? -1.0 : 1.0);
                    t.map[part][k] = l * l + l + m;
                    t.scl[part][k] = (float)(f * scale * fold);
                }
            }
            for (int m = 1; m <= l; ++m) {
                const int k = slot_i(part, l, m);
                const double scale =
                    csqrt(dfact(l + m) * dfact(l - m)) * csqrt((2 * l + 1) / (4.0 * PI_D));
                const double f    = csqrt(2.0) * ((m & 1) ? -1.0 : 1.0);
                const double fold = ((l - m) <= 1) ? 1.0 / (dfact(m) * dfact(l - m)) : 1.0;
                t.map[part][k] = l * l + l - m;
                t.scl[part][k] = (float)(f * scale * fold);
            }
        }
    }
    return t;
}

__constant__ Tables c_tab = make_tables();

// Load the pair of points {2*ip, 2*ip+1} as 3 x float2 (pairs start on 24-byte
// boundaries -> 8B aligned).  OOB points zero-fill; zero points contribute
// exactly zero downstream (w0 = 0 kills every term), so the math needs no
// guards and both points stay in one basic block.
__device__ __forceinline__ void load_pair(const float* __restrict__ pos, int ip, int n,
                                          float* __restrict__ c) {
    const int i0 = 2 * ip;
    if (i0 + 1 < n) {
        const float2* p2 = reinterpret_cast<const float2*>(pos + 3 * i0);
        const float2  a = p2[0], b = p2[1], d = p2[2];
        c[0] = a.x; c[1] = a.y; c[2] = b.x;
        c[3] = b.y; c[4] = d.x; c[5] = d.y;
    } else if (i0 < n) {
        c[0] = pos[3 * i0]; c[1] = pos[3 * i0 + 1]; c[2] = pos[3 * i0 + 2];
        c[3] = c[4] = c[5] = 0.f;
    } else {
        c[0] = c[1] = c[2] = c[3] = c[4] = c[5] = 0.f;
    }
}

}  // namespace

// Algebra (exact in fp up to reassociation):
//   z1 = (-x/2, -y/2), z2 = -conj(z1)  =>  one power table.
//   real term:  sr[p] - si[q];   imag p-sum collapses to zi[m]*Horner(rho).
//   T==1 (m >= l-1) pairs: coefficient folded into host-side scl.
//
// Round-3 lesson: beyond ~3 waves/SIMD, extra waves add NOTHING (VALUBusy
// stuck at 55% from 768 to 1536 blocks) — the stall is per-wave.  So this
// round processes TWO points per iteration, interleaved per-term: every
// coefficient materialization (VOP3 fma can't take literals -> each const
// costs a mov per use), every loop branch, and every address calc is shared
// by 2 points, and the two independent dep chains fill each other's latency
// bubbles.  Loads become 3 x float2 per pair instead of 6 scalars.
template <int PART>
__device__ __forceinline__ void sht_part(const float* __restrict__ pos,
                                         float* __restrict__ out, int n, int nblk) {
    constexpr int NA = nacc_part(PART);
    constexpr int PL = part_lmax(PART);
    constexpr int QX = PL / 2;  // max si index used: q <= (l-m)/2 <= PL/2
    constexpr int NL = nls(PART);

    float acc[NA];
#pragma unroll
    for (int k = 0; k < NA; ++k) acc[k] = 0.f;

    const int bid    = (int)(blockIdx.x >> 1);
    const int tid    = bid * 256 + (int)threadIdx.x;
    const int stride = nblk * 256;  // in pairs
    const int npair  = (n + 1) >> 1;

    float cur[6];
    int   ip = tid;
    load_pair(pos, ip, n, cur);

    while (ip < npair) {
        // software-pipelined prefetch of the next pair
        const int inext = ip + stride;
        float     nxt[6];
        load_pair(pos, inext, n, nxt);

        const float X[2] = {cur[0], cur[3]};
        const float Y[2] = {cur[1], cur[4]};
        const float Z[2] = {cur[2], cur[5]};

        float nrm[2], w0[2], ar[2], ai[2], rho[2];
#pragma unroll
        for (int j = 0; j < 2; ++j) {
            const float r2 = X[j] * X[j] + Y[j] * Y[j] + Z[j] * Z[j];
            nrm[j] = sqrtf(r2);
            w0[j]  = (nrm[j] > 0.f) ? Z[j] : 0.f;  // x0 * mask
            ar[j]  = -0.5f * X[j];
            ai[j]  = -0.5f * Y[j];
            rho[j] = ar[j] * ar[j] + ai[j] * ai[j];  // |z1|^2
        }

        // Power tables per point: zi[] full, sr[p]=Re^2 full, si[p]=Im^2 only
        // to QX.  Re(z1^p) is a rolling scalar.
        float zi[2][PL + 1], sr[2][PL + 1], si[2][QX + 1], zrc[2];
#pragma unroll
        for (int j = 0; j < 2; ++j) {
            zi[j][0] = 0.f;
            sr[j][0] = 1.f;
            si[j][0] = 0.f;
            zrc[j]   = 1.f;
        }
#pragma unroll
        for (int p = 1; p <= PL; ++p) {
#pragma unroll
            for (int j = 0; j < 2; ++j) {
                const float nzr = ar[j] * zrc[j] - ai[j] * zi[j][p - 1];
                zi[j][p]        = ar[j] * zi[j][p - 1] + ai[j] * zrc[j];
                zrc[j]          = nzr;
                sr[j][p]        = zrc[j] * zrc[j];
                if (p <= QX) si[j][p] = zi[j][p] * zi[j][p];  // folded at unroll
            }
        }

        // wrl = w0 * nrm^l for only the part's l values (minimal mul chain,
        // no full rp[] table -> less register pressure).
        float wl[2][NL];
#pragma unroll
        for (int j = 0; j < 2; ++j) {
            if constexpr (PART == 0) {  // ls = {2,3,6,7,10}
                const float n1 = nrm[j], n2 = n1 * n1, n3 = n2 * n1;
                const float n6 = n3 * n3, n7 = n6 * n1, n10 = n7 * n3;
                wl[j][0] = w0[j] * n2;
                wl[j][1] = w0[j] * n3;
                wl[j][2] = w0[j] * n6;
                wl[j][3] = w0[j] * n7;
                wl[j][4] = w0[j] * n10;
            } else {  // ls = {0,1,4,5,8,9}
                const float n1 = nrm[j], n2 = n1 * n1, n4 = n2 * n2;
                const float n5 = n4 * n1, n8 = n4 * n4, n9 = n8 * n1;
                wl[j][0] = w0[j];
                wl[j][1] = w0[j] * n1;
                wl[j][2] = w0[j] * n4;
                wl[j][3] = w0[j] * n5;
                wl[j][4] = w0[j] * n8;
                wl[j][5] = w0[j] * n9;
            }
        }

#pragma unroll
        for (int l = 0; l <= LMAX; ++l) {
            if (PART_OF_L[l] != PART) continue;  // compile-time eliminated
            const int li = lidx(PART, l);
#pragma unroll
            for (int m = 0; m <= l; ++m) {
                const int Q = (l - m) >> 1;  // highest q in the sums
                if (m >= 1 && Q == 0) {
                    // single-term pair: coefficient folded into c_tab.scl
#pragma unroll
                    for (int j = 0; j < 2; ++j)
                        acc[slot_r(PART, l, m)] += sr[j][m] * wl[j][li];
#pragma unroll
                    for (int j = 0; j < 2; ++j)
                        acc[slot_i(PART, l, m)] += zi[j][m] * wl[j][li];
                } else {
                    float shr[2] = {0.f, 0.f};
#pragma unroll
                    for (int p = m; 2 * p <= l + m; ++p) {
                        const int   q  = p - m;
                        const float cr = (float)(1.0 / (FACT[p] * FACT[q] * FACT[l - 2 * p + m]));
#pragma unroll
                        for (int j = 0; j < 2; ++j) shr[j] += (sr[j][p] - si[j][q]) * cr;
                    }
#pragma unroll
                    for (int j = 0; j < 2; ++j)
                        acc[slot_r(PART, l, m)] += shr[j] * wl[j][li];
                    if (m >= 1) {
                        // shi = zi[m] * Horner_q(+-c * rho^q)
                        float t[2];
                        t[0] = t[1] = ci_coef(l, m, Q);
#pragma unroll
                        for (int q = Q - 1; q >= 0; --q) {
                            const float c = ci_coef(l, m, q);
#pragma unroll
                            for (int j = 0; j < 2; ++j) t[j] = t[j] * rho[j] + c;
                        }
#pragma unroll
                        for (int j = 0; j < 2; ++j)
                            acc[slot_i(PART, l, m)] += (t[j] * zi[j][m]) * wl[j][li];
                    }
                }
            }
        }

        ip = inext;
#pragma unroll
        for (int k = 0; k < 6; ++k) cur[k] = nxt[k];
    }

    // Wave (64-lane) shuffle reduction, then cross-wave via LDS.
    __shared__ float red[4][NA];
    const int lane = threadIdx.x & 63;
    const int wav  = threadIdx.x >> 6;
#pragma unroll
    for (int k = 0; k < NA; ++k) {
        float v = acc[k];
#pragma unroll
        for (int off = 32; off > 0; off >>= 1) v += __shfl_down(v, off, 64);
        if (lane == 0) red[wav][k] = v;
    }
    __syncthreads();
    if ((int)threadIdx.x < NA) {
        const int   k = (int)threadIdx.x;
        const float v = red[0][k] + red[1][k] + red[2][k] + red[3][k];
        atomicAdd(&out[c_tab.map[PART][k]], v * c_tab.scl[PART][k]);
    }
}

__global__ __launch_bounds__(256, 2) void sht_kernel(const float* __restrict__ pos,
                                                     float* __restrict__ out, int n, int nblk) {
    // part = blockIdx & 1: stride-256 round-robin keeps one part per CU (I$).
    if (blockIdx.x & 1)
        sht_part<1>(pos, out, n, nblk);
    else
        sht_part<0>(pos, out, n, nblk);
}

extern "C" void kernel_launch(void* const* d_in, const int* in_sizes, int n_in,
                              void* d_out, int out_size, void* d_ws, size_t ws_size,
                              hipStream_t stream) {
    const float* pos = (const float*)d_in[0];
    float* out       = (float*)d_out;
    const int n      = in_sizes[0] / 3;  // (N,3) flat -> N points

    // d_out is poisoned before every launch; we accumulate via atomics.
    hipMemsetAsync(d_out, 0, (size_t)out_size * sizeof(float), stream);

    const int threads = 256;
    // Revert to the round-2 winner: 384 blocks/part = 3 blocks/CU.  Round 3
    // proved extra waves beyond this add no overlap (VALUBusy flat at 55%)
    // and just double the epilogue cost.  ILP now comes from the 2-pt unroll.
    const int nblk_per_part = 384;
    const int blocks        = NPART * nblk_per_part;  // 768
    sht_kernel<<<blocks, threads, 0, stream>>>(pos, out, n, nblk_per_part);
}